// Round 18
// baseline (56.843 us; speedup 1.0000x reference)
//
#include <hip/hip_runtime.h>

typedef _Float16 f16;
typedef __attribute__((ext_vector_type(8))) _Float16 f16x8;
typedef __attribute__((ext_vector_type(4))) float f32x4;
typedef __attribute__((ext_vector_type(4))) unsigned int u32x4;
typedef __attribute__((ext_vector_type(8))) unsigned short ushort8;

#define QF   64
#define GG   120
#define HID  128
#define NACT 20
#define BTOT 2048

// ---- workspace layout (bytes) ----
#define WEFF_OFF 0u           // 120 * 16KB f16 frag-order = 1,966,080
#define W1F_OFF  1966080u     // 32KB f16 frag-order (k-permuted)
#define MISC_OFF 1998848u     // bmean[128], wmean[128], cb (1088 B)
#define ABUF_OFF 1999936u     // A_canon: 5*64*128 f32 = 163,840

template <typename T>
__device__ __forceinline__ void keepv(T& v) { asm volatile("" : "+v"(v)); }

// ---- packed-nibble permutation helpers (register-only) ----
__device__ __forceinline__ unsigned idx_to_packed(int i) {
    unsigned avail = 0x43210u, pp = 0u;
    const int fct[4] = {24, 6, 2, 1};
#pragma unroll
    for (int k = 0; k < 4; ++k) {
        int d = i / fct[k]; i -= d * fct[k];
        pp |= ((avail >> (4 * d)) & 0xFu) << (4 * k);
        unsigned mask = (1u << (4 * d)) - 1u;
        avail = (avail & mask) | ((avail >> 4) & ~mask);
    }
    pp |= (avail & 0xFu) << 16;
    return pp;
}

__device__ __forceinline__ int packed_to_idx(unsigned pp) {
    const int fct[4] = {24, 6, 2, 1};
    int idx = 0;
#pragma unroll
    for (int k = 0; k < 4; ++k) {
        unsigned pk = (pp >> (4 * k)) & 0xFu;
        int c = 0;
#pragma unroll
        for (int j = k + 1; j < 5; ++j)
            c += (int)(((pp >> (4 * j)) & 0xFu) < pk);
        idx += c * fct[k];
    }
    return idx;
}

__device__ __forceinline__ unsigned compose_packed(unsigned pa, unsigned pb) {
    unsigned pc = 0;
#pragma unroll
    for (int k = 0; k < 5; ++k) {
        unsigned bk = (pb >> (4 * k)) & 0xFu;
        pc |= ((pa >> (4 * bk)) & 0xFu) << (4 * k);
    }
    return pc;
}

__device__ __forceinline__ unsigned invert_packed(unsigned pp) {
    unsigned pi = 0;
#pragma unroll
    for (int k = 0; k < 5; ++k)
        pi |= (unsigned)k << (4 * ((pp >> (4 * k)) & 0xFu));
    return pi;
}

// i-th element of S4 (perms of {0,1,2,3}, slot4 = 4), packed
__device__ __forceinline__ unsigned s4_packed(int i) {
    unsigned avail = 0x3210u, pp = 0u;
    const int f3[3] = {6, 2, 1};
#pragma unroll
    for (int k = 0; k < 3; ++k) {
        int d = i / f3[k]; i -= d * f3[k];
        pp |= ((avail >> (4 * d)) & 0xFu) << (4 * k);
        unsigned mask = (1u << (4 * d)) - 1u;
        avail = (avail & mask) | ((avail >> 4) & ~mask);
    }
    pp |= (avail & 0xFu) << 12;
    pp |= 4u << 16;
    return pp;
}

// transposition (t 4); t=4 -> identity (self-inverse)
__device__ __forceinline__ unsigned crep_pp(int t) {
    unsigned pp = 0x43210u;
    pp &= ~(0xFu << (4 * t));
    pp &= ~(0xFu << 16);
    pp |= 4u << (4 * t);
    pp |= (unsigned)t << 16;
    return pp;
}

// fpt[v][r] with ppi = v^-1 packed
__device__ __forceinline__ int bitperm_r(unsigned ppi, int r) {
    int val = r & 32;
#pragma unroll
    for (int k = 0; k < 5; ++k) {
        int pik = (ppi >> (4 * k)) & 0xF;
        val |= ((r >> (4 - pik)) & 1) << (4 - k);
    }
    return val;
}

// e-th member (e in 0..5) of coset a (perms with p0=i, p1=j), as perm index
__device__ __forceinline__ int coset_member(int a, int e) {
    int i = a >> 2, jj = a & 3;
    int j = jj + (jj >= i ? 1 : 0);
    unsigned mask = 0x1Fu & ~(1u << i) & ~(1u << j);
    int d0 = __builtin_ctz(mask); mask &= mask - 1u;
    int d1 = __builtin_ctz(mask); mask &= mask - 1u;
    int d2 = __builtin_ctz(mask);
    int k0 = e >> 1;
    int p2 = k0 == 0 ? d0 : (k0 == 1 ? d1 : d2);
    int r0 = k0 == 0 ? d1 : d0;
    int r1 = k0 == 2 ? d1 : d2;
    int p3 = (e & 1) ? r1 : r0;
    int p4 = (e & 1) ? r0 : r1;
    unsigned pp = (unsigned)i | ((unsigned)j << 4) | ((unsigned)p2 << 8)
                | ((unsigned)p3 << 12) | ((unsigned)p4 << 16);
    return packed_to_idx(pp);
}

__device__ __forceinline__ unsigned short f2h(float f) {
    f16 h = (f16)f;
    return __builtin_bit_cast(unsigned short, h);
}
// pack two floats to f16 pair (RTN) in a u32
__device__ __forceinline__ unsigned pk2(float a, float b) {
    return (unsigned)f2h(a) | ((unsigned)f2h(b) << 16);
}

__device__ __forceinline__ f32x4 mfma16(f16x8 a, f16x8 b, f32x4 c) {
    return __builtin_amdgcn_mfma_f32_16x16x32_f16(a, b, c, 0, 0, 0);
}

// K1: A_canon[c] = A[crep_c] (5 canonical matrices). 40 blocks x 256 thr.
__global__ void k1_acanon(const float* __restrict__ eqw, float* __restrict__ Acan) {
    __shared__ int sg[24];
    __shared__ int sq[24][8];
    int b = blockIdx.x, t = threadIdx.x;
    int c = b >> 3, rbase = (b & 7) * 8;
    if (t < 24) sg[t] = packed_to_idx(compose_packed(s4_packed(t), crep_pp(c)));
    if (t < 192) {
        int si = t >> 3;
        sq[si][t & 7] = bitperm_r(invert_packed(s4_packed(si)), rbase + (t & 7));
    }
    __syncthreads();
    int h4 = (t & 31) * 4, rslot = t >> 5;
    f32x4 acc = {0.f, 0.f, 0.f, 0.f};
#pragma unroll
    for (int si = 0; si < 24; ++si) {
        f32x4 v = *(const f32x4*)(eqw + (unsigned)(sg[si] * QF + sq[si][rslot]) * HID + h4);
        acc = acc + v;
    }
    *(f32x4*)(Acan + (unsigned)(c * QF + rbase + rslot) * HID + h4) = acc;
}

// K2: blocks [0,120): Weff[u] f16 A-frags from A_canon.
//     blocks [120,128): W1 -> f16 B-frags (k-permuted).  block 128: misc.
__global__ void k2_weff(const float* __restrict__ Acan, const float* __restrict__ W1,
                        const float* __restrict__ eq_bias, const float* __restrict__ Wout,
                        const float* __restrict__ bout,
                        unsigned short* __restrict__ weff,
                        unsigned short* __restrict__ w1f, float* __restrict__ misc) {
    __shared__ float Wacc[HID][QF + 1];
    __shared__ int rp[5][64];
    int b = blockIdx.x, t = threadIdx.x;
    if (b < 120) {
        int u = b;
        unsigned upk = idx_to_packed(u);
        for (int i = t; i < 5 * 64; i += 256)
            rp[i >> 6][i & 63] = bitperm_r(compose_packed(upk, crep_pp(i >> 6)), i & 63);
        __syncthreads();
        int h = t & 127, qg = t >> 7;
        for (int i = 0; i < 32; ++i) {
            int q = qg * 32 + i;
            float s = 0.f;
#pragma unroll
            for (int c = 0; c < 5; ++c)
                s += Acan[(unsigned)(c * QF + rp[c][q]) * HID + h];
            Wacc[h][q] = s * (1.f / GG);
        }
        __syncthreads();
        for (int e = t; e < 1024; e += 256) {
            int fg = e >> 6, lane = e & 63;
            int hm = fg >> 1, ks = fg & 1;
            int hh = hm * 16 + (lane & 15), q0 = ks * 32 + (lane >> 4) * 8;
            ushort8 v;
#pragma unroll
            for (int j = 0; j < 8; ++j) v[j] = f2h(Wacc[hh][q0 + j]);
            *(ushort8*)(weff + (unsigned)(u * 16 + fg) * 64 * 8 + lane * 8) = v;
        }
    } else if (b < 128) {                 // W1 -> f16 B-frags, k-permuted
        int idx = (b - 120) * 256 + t;    // < 2048
        int fg = idx >> 6, lane = idx & 63;
        int nt = fg >> 2, ks = fg & 3;
        int n = nt * 16 + (lane & 15), kg = lane >> 4;
        ushort8 v;
#pragma unroll
        for (int j = 0; j < 8; ++j) {
            int h = ks * 32 + ((j >> 2) << 4) + (kg << 2) + (j & 3);
            v[j] = f2h(W1[h * HID + n]);
        }
        *(ushort8*)(w1f + idx * 8) = v;
    } else {                              // misc
        if (t < HID) {
            float s = 0.f;
            for (int g = 0; g < GG; ++g) s += eq_bias[g * HID + t];
            misc[t] = s * (1.f / GG);
            float wv = 0.f;
            for (int n = 0; n < NACT; ++n) wv += Wout[t * NACT + n];
            misc[HID + t] = wv * (1.f / NACT);
            if (t == 0) {
                float c = 0.f;
                for (int n = 0; n < NACT; ++n) c += bout[n];
                misc[2 * HID] = c * (1.f / NACT);
            }
        }
    }
}

// K3: fused MLP + coset reduce, barrier-free u-loop. 640 blocks (XCD-chunked)
// x 128 thr. weff streams global->reg 8 frags at a time (short live range —
// the R15 fix); only W1+misc in LDS (33.8KB -> 4 blocks/CU, whole grid
// resident in one round); zero barriers after init.
__global__ __launch_bounds__(128, 2)
void mlp_mfma(const float* __restrict__ x,
              const unsigned short* __restrict__ weff,
              const unsigned short* __restrict__ w1f,
              const float* __restrict__ b1,
              const float* __restrict__ misc,
              float* __restrict__ out) {
    __shared__ __align__(16) unsigned short w1s[16384];      // 32KB
    __shared__ float miscs[2 * HID];
    __shared__ float b1s[HID];

    int bid0 = blockIdx.x;
    int bid = (bid0 & 7) * 80 + (bid0 >> 3);   // XCD-chunked, bijective (640=8*80)
    int tile = bid & 31, a = bid >> 5;
    int rowbase = tile * 64;
    int t = threadIdx.x;                  // 0..127
    int w = t >> 6, lane = t & 63;
    int lm = lane & 15, kg = lane >> 4;
    int xbase = rowbase + w * 32;

#pragma unroll
    for (int i = 0; i < 16; ++i)
        *(u32x4*)(w1s + (i * 128 + t) * 8) = *(const u32x4*)(w1f + (i * 128 + t) * 8);
    miscs[t] = misc[t];
    miscs[128 + t] = misc[128 + t];
    b1s[t] = b1[t];
    float cb = misc[2 * HID];

    // X frags (B-operand of swapped stage A): load f32, convert RTN in-register
    f16x8 xb[2][2];
#pragma unroll
    for (int xt = 0; xt < 2; ++xt)
#pragma unroll
        for (int ks = 0; ks < 2; ++ks) {
            const float* xp = x + (unsigned)(xbase + xt * 16 + lm) * QF + ks * 32 + kg * 8;
            f32x4 a0 = *(const f32x4*)xp;
            f32x4 a1 = *(const f32x4*)(xp + 4);
            ushort8 v;
            v[0] = f2h(a0[0]); v[1] = f2h(a0[1]); v[2] = f2h(a0[2]); v[3] = f2h(a0[3]);
            v[4] = f2h(a1[0]); v[5] = f2h(a1[1]); v[6] = f2h(a1[2]); v[7] = f2h(a1[3]);
            xb[xt][ks] = __builtin_bit_cast(f16x8, v);
            keepv(xb[xt][ks]);
        }
    __syncthreads();   // the ONLY barrier: w1s/miscs ready (read-only after)

    float macc[2][4];
#pragma unroll
    for (int xt = 0; xt < 2; ++xt)
#pragma unroll
        for (int r = 0; r < 4; ++r) macc[xt][r] = 0.f;

#pragma unroll 1
    for (int ui = 0; ui < 6; ++ui) {
        int u = coset_member(a, ui);
        const unsigned short* wsrc = weff + (unsigned)u * 8192;

        f32x4 acc2[2][8];
#pragma unroll
        for (int xt = 0; xt < 2; ++xt)
#pragma unroll
            for (int nt = 0; nt < 8; ++nt) acc2[xt][nt] = (f32x4){0.f, 0.f, 0.f, 0.f};

#pragma unroll
        for (int half = 0; half < 2; ++half) {
            // ---- load this half's 8 weff frags (short live range) ----
            f16x8 wfr[8];
#pragma unroll
            for (int f = 0; f < 8; ++f)
                wfr[f] = *(const f16x8*)(wsrc + ((half * 8 + f) * 64 + lane) * 8);

            // ---- stage A (swapped) for hm in this half ----
            f32x4 acc[2][4];
#pragma unroll
            for (int xt = 0; xt < 2; ++xt)
#pragma unroll
                for (int hl = 0; hl < 4; ++hl) acc[xt][hl] = (f32x4){0.f, 0.f, 0.f, 0.f};
#pragma unroll
            for (int hl = 0; hl < 4; ++hl)
#pragma unroll
                for (int ks = 0; ks < 2; ++ks)
#pragma unroll
                    for (int xt = 0; xt < 2; ++xt)
                        acc[xt][hl] = mfma16(wfr[hl * 2 + ks], xb[xt][ks], acc[xt][hl]);

            // ---- epilogue A + stage B for this half's two k-slices ----
#pragma unroll
            for (int ksl = 0; ksl < 2; ++ksl) {
                int ksp = 2 * half + ksl;            // stage-B k-slice
                int hg0 = 4 * half + 2 * ksl;        // global hm of acc pair
                f32x4 bm0 = *(const f32x4*)(miscs + hg0 * 16 + kg * 4);
                f32x4 bm1 = *(const f32x4*)(miscs + (hg0 + 1) * 16 + kg * 4);
                f16x8 pa[2];
#pragma unroll
                for (int xt = 0; xt < 2; ++xt) {
                    f32x4 e0 = acc[xt][2 * ksl] + bm0;
                    f32x4 e1 = acc[xt][2 * ksl + 1] + bm1;
#pragma unroll
                    for (int r = 0; r < 4; ++r) {
                        e0[r] = e0[r] > 0.f ? e0[r] : 0.f;
                        e1[r] = e1[r] > 0.f ? e1[r] : 0.f;
                    }
                    u32x4 ph = {pk2(e0[0], e0[1]), pk2(e0[2], e0[3]),
                                pk2(e1[0], e1[1]), pk2(e1[2], e1[3])};
                    pa[xt] = __builtin_bit_cast(f16x8, ph);
                }
#pragma unroll
                for (int nt = 0; nt < 8; ++nt) {
                    f16x8 wb = *(const f16x8*)(w1s + ((nt * 4 + ksp) * 64 + lane) * 8);
#pragma unroll
                    for (int xt = 0; xt < 2; ++xt)
                        acc2[xt][nt] = mfma16(pa[xt], wb, acc2[xt][nt]);
                }
            }
        }

        // ---- epilogue B: accumulate relu(h2+b1).wmean into macc ----
#pragma unroll
        for (int nt = 0; nt < 8; ++nt) {
            float bb = b1s[nt * 16 + lm];
            float wm = miscs[HID + nt * 16 + lm];
#pragma unroll
            for (int xt = 0; xt < 2; ++xt)
#pragma unroll
                for (int r = 0; r < 4; ++r) {
                    float v = acc2[xt][nt][r] + bb;
                    v = v > 0.f ? v : 0.f;
                    macc[xt][r] += v * wm;
                }
        }
    }

    // one 16-lane reduce for the whole coset sum
#pragma unroll
    for (int off = 1; off < 16; off <<= 1)
#pragma unroll
        for (int xt = 0; xt < 2; ++xt)
#pragma unroll
            for (int r = 0; r < 4; ++r)
                macc[xt][r] += __shfl_xor(macc[xt][r], off, 64);
    if (lm == 0) {
#pragma unroll
        for (int xt = 0; xt < 2; ++xt)
#pragma unroll
            for (int r = 0; r < 4; ++r)
                out[(unsigned)(xbase + xt * 16 + kg * 4 + r) * NACT + a] =
                    macc[xt][r] * (1.f / 6.f) + cb;
    }
}

extern "C" void kernel_launch(void* const* d_in, const int* in_sizes, int n_in,
                              void* d_out, int out_size, void* d_ws, size_t ws_size,
                              hipStream_t stream) {
    const float* x       = (const float*)d_in[0];
    const float* eqw     = (const float*)d_in[1];
    const float* eq_bias = (const float*)d_in[2];
    const float* W1      = (const float*)d_in[3];
    const float* b1      = (const float*)d_in[4];
    const float* Wout    = (const float*)d_in[5];
    const float* bout    = (const float*)d_in[6];
    float* out           = (float*)d_out;

    char* ws = (char*)d_ws;
    unsigned short* weff = (unsigned short*)(ws + WEFF_OFF);
    unsigned short* w1f  = (unsigned short*)(ws + W1F_OFF);
    float* misc   = (float*)(ws + MISC_OFF);
    float* Acan   = (float*)(ws + ABUF_OFF);

    hipLaunchKernelGGL(k1_acanon, dim3(40), dim3(256), 0, stream, eqw, Acan);
    hipLaunchKernelGGL(k2_weff, dim3(129), dim3(256), 0, stream,
                       Acan, W1, eq_bias, Wout, bout, weff, w1f, misc);
    hipLaunchKernelGGL(mlp_mfma, dim3(640), dim3(128), 0, stream,
                       x, weff, w1f, b1, misc, out);
}

// Round 19
// 41.292 us; speedup vs baseline: 1.3766x; 1.3766x over previous
//
#include <hip/hip_runtime.h>

typedef _Float16 f16;
typedef __attribute__((ext_vector_type(8))) _Float16 f16x8;
typedef __attribute__((ext_vector_type(4))) float f32x4;
typedef __attribute__((ext_vector_type(4))) unsigned int u32x4;
typedef __attribute__((ext_vector_type(8))) unsigned short ushort8;

#define QF   64
#define GG   120
#define HID  128
#define NACT 20
#define BTOT 2048

// ---- workspace layout (bytes) ----
#define WEFF_OFF 0u           // 120 * 16KB f16 frag-order = 1,966,080
#define XH_OFF   1966080u     // 2048*64 f16 = 262,144
#define W1F_OFF  2490368u     // 32KB f16 frag-order (k-permuted)
#define MISC_OFF 2523136u     // bmean[128], wmean[128], cb (1088 B)
#define ABUF_OFF 2524224u     // A_canon: 5*64*128 f32 = 163,840

template <typename T>
__device__ __forceinline__ void keepv(T& v) { asm volatile("" : "+v"(v)); }

// ---- packed-nibble permutation helpers (register-only) ----
__device__ __forceinline__ unsigned idx_to_packed(int i) {
    unsigned avail = 0x43210u, pp = 0u;
    const int fct[4] = {24, 6, 2, 1};
#pragma unroll
    for (int k = 0; k < 4; ++k) {
        int d = i / fct[k]; i -= d * fct[k];
        pp |= ((avail >> (4 * d)) & 0xFu) << (4 * k);
        unsigned mask = (1u << (4 * d)) - 1u;
        avail = (avail & mask) | ((avail >> 4) & ~mask);
    }
    pp |= (avail & 0xFu) << 16;
    return pp;
}

__device__ __forceinline__ int packed_to_idx(unsigned pp) {
    const int fct[4] = {24, 6, 2, 1};
    int idx = 0;
#pragma unroll
    for (int k = 0; k < 4; ++k) {
        unsigned pk = (pp >> (4 * k)) & 0xFu;
        int c = 0;
#pragma unroll
        for (int j = k + 1; j < 5; ++j)
            c += (int)(((pp >> (4 * j)) & 0xFu) < pk);
        idx += c * fct[k];
    }
    return idx;
}

__device__ __forceinline__ unsigned compose_packed(unsigned pa, unsigned pb) {
    unsigned pc = 0;
#pragma unroll
    for (int k = 0; k < 5; ++k) {
        unsigned bk = (pb >> (4 * k)) & 0xFu;
        pc |= ((pa >> (4 * bk)) & 0xFu) << (4 * k);
    }
    return pc;
}

__device__ __forceinline__ unsigned invert_packed(unsigned pp) {
    unsigned pi = 0;
#pragma unroll
    for (int k = 0; k < 5; ++k)
        pi |= (unsigned)k << (4 * ((pp >> (4 * k)) & 0xFu));
    return pi;
}

// i-th element of S4 (perms of {0,1,2,3}, slot4 = 4), packed
__device__ __forceinline__ unsigned s4_packed(int i) {
    unsigned avail = 0x3210u, pp = 0u;
    const int f3[3] = {6, 2, 1};
#pragma unroll
    for (int k = 0; k < 3; ++k) {
        int d = i / f3[k]; i -= d * f3[k];
        pp |= ((avail >> (4 * d)) & 0xFu) << (4 * k);
        unsigned mask = (1u << (4 * d)) - 1u;
        avail = (avail & mask) | ((avail >> 4) & ~mask);
    }
    pp |= (avail & 0xFu) << 12;
    pp |= 4u << 16;
    return pp;
}

// transposition (t 4); t=4 -> identity (self-inverse)
__device__ __forceinline__ unsigned crep_pp(int t) {
    unsigned pp = 0x43210u;
    pp &= ~(0xFu << (4 * t));
    pp &= ~(0xFu << 16);
    pp |= 4u << (4 * t);
    pp |= (unsigned)t << 16;
    return pp;
}

// fpt[v][r] with ppi = v^-1 packed: output bit (4-k) = r bit (4-ppi[k]); top bit kept
__device__ __forceinline__ int bitperm_r(unsigned ppi, int r) {
    int val = r & 32;
#pragma unroll
    for (int k = 0; k < 5; ++k) {
        int pik = (ppi >> (4 * k)) & 0xF;
        val |= ((r >> (4 - pik)) & 1) << (4 - k);
    }
    return val;
}

// e-th member (e in 0..5) of coset a (perms with p0=i, p1=j), as perm index
__device__ __forceinline__ int coset_member(int a, int e) {
    int i = a >> 2, jj = a & 3;
    int j = jj + (jj >= i ? 1 : 0);
    unsigned mask = 0x1Fu & ~(1u << i) & ~(1u << j);
    int d0 = __builtin_ctz(mask); mask &= mask - 1u;
    int d1 = __builtin_ctz(mask); mask &= mask - 1u;
    int d2 = __builtin_ctz(mask);
    int k0 = e >> 1;
    int p2 = k0 == 0 ? d0 : (k0 == 1 ? d1 : d2);
    int r0 = k0 == 0 ? d1 : d0;
    int r1 = k0 == 2 ? d1 : d2;
    int p3 = (e & 1) ? r1 : r0;
    int p4 = (e & 1) ? r0 : r1;
    unsigned pp = (unsigned)i | ((unsigned)j << 4) | ((unsigned)p2 << 8)
                | ((unsigned)p3 << 12) | ((unsigned)p4 << 16);
    return packed_to_idx(pp);
}

__device__ __forceinline__ unsigned short f2h(float f) {
    f16 h = (f16)f;
    return __builtin_bit_cast(unsigned short, h);
}
// pack two floats to f16 pair (RTN) in a u32
__device__ __forceinline__ unsigned pk2(float a, float b) {
    return (unsigned)f2h(a) | ((unsigned)f2h(b) << 16);
}

// K1: fused prep. A_canon[c] = A[crep_c] (5 canonical matrices —
// A[s0∘y] = A[y]∘fpt[s0^-1] makes the other 115 redundant).
//  [0,40):    A_canon[c][r][h] = sum_{s in S4} eqw[s∘crep_c][fpt[s][r]][h]
//  [40,552):  x -> f16
//  [552,560): W1 -> f16 B-frags (k-permuted)
//  560:       misc
__global__ void prep_stage1(const float* __restrict__ x, const float* __restrict__ W1,
                            const float* __restrict__ eq_bias, const float* __restrict__ Wout,
                            const float* __restrict__ bout, const float* __restrict__ eqw,
                            float* __restrict__ misc,
                            unsigned short* __restrict__ xh,
                            unsigned short* __restrict__ w1f, float* __restrict__ Acan) {
    __shared__ int sg[24];
    __shared__ int sq[24][8];
    int b = blockIdx.x, t = threadIdx.x;
    if (b < 40) {
        int c = b >> 3, rbase = (b & 7) * 8;
        if (t < 24) sg[t] = packed_to_idx(compose_packed(s4_packed(t), crep_pp(c)));
        if (t < 192) {
            int si = t >> 3;
            sq[si][t & 7] = bitperm_r(invert_packed(s4_packed(si)), rbase + (t & 7));
        }
        __syncthreads();
        int h4 = (t & 31) * 4, rslot = t >> 5;
        f32x4 acc = {0.f, 0.f, 0.f, 0.f};
#pragma unroll
        for (int si = 0; si < 24; ++si) {
            f32x4 v = *(const f32x4*)(eqw + (unsigned)(sg[si] * QF + sq[si][rslot]) * HID + h4);
            acc = acc + v;
        }
        *(f32x4*)(Acan + (unsigned)(c * QF + rbase + rslot) * HID + h4) = acc;
    } else if (b < 552) {                 // x -> f16 (single, RTN)
        int idx = (b - 40) * 256 + t;     // < 131072
        xh[idx] = f2h(x[idx]);
    } else if (b < 560) {                 // W1 -> f16 B-frags, k-permuted
        int idx = (b - 552) * 256 + t;    // < 2048
        int fg = idx >> 6, lane = idx & 63;
        int nt = fg >> 2, ks = fg & 3;
        int n = nt * 16 + (lane & 15), kg = lane >> 4;
        ushort8 v;
#pragma unroll
        for (int j = 0; j < 8; ++j) {
            int h = ks * 32 + ((j >> 2) << 4) + (kg << 2) + (j & 3);
            v[j] = f2h(W1[h * HID + n]);
        }
        *(ushort8*)(w1f + idx * 8) = v;
    } else {                              // misc
        if (t < HID) {
            float s = 0.f;
            for (int g = 0; g < GG; ++g) s += eq_bias[g * HID + t];
            misc[t] = s * (1.f / GG);
            float wv = 0.f;
            for (int n = 0; n < NACT; ++n) wv += Wout[t * NACT + n];
            misc[HID + t] = wv * (1.f / NACT);
            if (t == 0) {
                float c = 0.f;
                for (int n = 0; n < NACT; ++n) c += bout[n];
                misc[2 * HID] = c * (1.f / NACT);
            }
        }
    }
}

// K2: Weff[u][q][h] = (1/G) sum_{c=0..4} A_canon[c][fpt[crep_c∘u^-1][q]][h]
// Emit f16 A-frags: [hm(8)][ks(2)][lane(64)] x ushort8; q = ks*32+(lane>>4)*8+j,
// h = hm*16 + (lane&15)
__global__ void weff_stage2(const float* __restrict__ Acan,
                            unsigned short* __restrict__ weff) {
    __shared__ float Wacc[HID][QF + 1];
    __shared__ int rp[5][64];
    int u = blockIdx.x, t = threadIdx.x;
    unsigned upk = idx_to_packed(u);
    for (int i = t; i < 5 * 64; i += 256)
        rp[i >> 6][i & 63] = bitperm_r(compose_packed(upk, crep_pp(i >> 6)), i & 63);
    __syncthreads();
    int h = t & 127, qg = t >> 7;
    for (int i = 0; i < 32; ++i) {
        int q = qg * 32 + i;
        float s = 0.f;
#pragma unroll
        for (int c = 0; c < 5; ++c)
            s += Acan[(unsigned)(c * QF + rp[c][q]) * HID + h];
        Wacc[h][q] = s * (1.f / GG);
    }
    __syncthreads();
    for (int e = t; e < 1024; e += 256) {
        int fg = e >> 6, lane = e & 63;
        int hm = fg >> 1, ks = fg & 1;
        int hh = hm * 16 + (lane & 15), q0 = ks * 32 + (lane >> 4) * 8;
        ushort8 v;
#pragma unroll
        for (int j = 0; j < 8; ++j) v[j] = f2h(Wacc[hh][q0 + j]);
        *(ushort8*)(weff + (unsigned)(u * 16 + fg) * 64 * 8 + lane * 8) = v;
    }
}

__device__ __forceinline__ f32x4 mfma16(f16x8 a, f16x8 b, f32x4 c) {
    return __builtin_amdgcn_mfma_f32_16x16x32_f16(a, b, c, 0, 0, 0);
}

// K3: fused MLP + coset reduce, pure f16. 640 blocks (32 row-tiles x 20 cosets)
// x 128 thr (2 waves x 32 rows). XCD-chunked remap: each XCD sees ~2.5 cosets'
// weff (L2-local). W1 32K + weff 16K in LDS; reg-prefetch next-u weff.
__global__ __launch_bounds__(128, 2)
void mlp_mfma(const unsigned short* __restrict__ xh,
              const unsigned short* __restrict__ weff,
              const unsigned short* __restrict__ w1f,
              const float* __restrict__ b1,
              const float* __restrict__ misc,
              float* __restrict__ out) {
    __shared__ __align__(16) unsigned short w1s[16384];      // 32KB
    __shared__ __align__(16) unsigned short wefs[8192];      // 16KB
    __shared__ float miscs[2 * HID];
    __shared__ float b1s[HID];

    int bid0 = blockIdx.x;
    int bid = (bid0 & 7) * 80 + (bid0 >> 3);   // XCD-chunked, bijective (640=8*80)
    int tile = bid & 31, a = bid >> 5;
    int rowbase = tile * 64;
    int t = threadIdx.x;                  // 0..127
    int w = t >> 6, lane = t & 63;
    int lm = lane & 15, kg = lane >> 4;
    int xbase = rowbase + w * 32;

    int u0 = coset_member(a, 0);
#pragma unroll
    for (int i = 0; i < 16; ++i)
        *(u32x4*)(w1s + (i * 128 + t) * 8) = *(const u32x4*)(w1f + (i * 128 + t) * 8);
#pragma unroll
    for (int i = 0; i < 8; ++i)
        *(u32x4*)(wefs + (i * 128 + t) * 8) =
            *(const u32x4*)(weff + (unsigned)u0 * 8192 + (i * 128 + t) * 8);
    miscs[t] = misc[t];
    miscs[128 + t] = misc[128 + t];
    b1s[t] = b1[t];
    float cb = misc[2 * HID];

    // pin X frags (B-operand of swapped stage A): [xt][ks], single f16
    f16x8 xb[2][2];
#pragma unroll
    for (int xt = 0; xt < 2; ++xt)
#pragma unroll
        for (int ks = 0; ks < 2; ++ks) {
            int off = (xbase + xt * 16 + lm) * QF + ks * 32 + kg * 8;
            xb[xt][ks] = *(const f16x8*)(xh + off);
            keepv(xb[xt][ks]);
        }
    __syncthreads();

    float macc[2][4];
#pragma unroll
    for (int xt = 0; xt < 2; ++xt)
#pragma unroll
        for (int r = 0; r < 4; ++r) macc[xt][r] = 0.f;

#pragma unroll 1
    for (int ui = 0; ui < 6; ++ui) {
        bool hasNext = (ui < 5);
        u32x4 pf[8];
        if (hasNext) {
            int un = coset_member(a, ui + 1);
            const unsigned short* wsrc = weff + (unsigned)un * 8192;
#pragma unroll
            for (int i = 0; i < 8; ++i)
                pf[i] = *(const u32x4*)(wsrc + (i * 128 + t) * 8);
        }

        // ---- stage A (swapped): lane holds E for x-row xbase+xt*16+lm,
        //      h = hm*16 + kg*4 + r
        f32x4 acc[2][8];
#pragma unroll
        for (int xt = 0; xt < 2; ++xt)
#pragma unroll
            for (int hm = 0; hm < 8; ++hm) acc[xt][hm] = (f32x4){0.f, 0.f, 0.f, 0.f};
#pragma unroll
        for (int hm = 0; hm < 8; ++hm)
#pragma unroll
            for (int ks = 0; ks < 2; ++ks) {
                f16x8 wf = *(const f16x8*)(wefs + ((hm * 2 + ks) * 64 + lane) * 8);
#pragma unroll
                for (int xt = 0; xt < 2; ++xt)
                    acc[xt][hm] = mfma16(wf, xb[xt][ks], acc[xt][hm]);
            }

        __syncthreads();   // all waves done reading wefs
        if (hasNext) {
#pragma unroll
            for (int i = 0; i < 8; ++i)
                *(u32x4*)(wefs + (i * 128 + t) * 8) = pf[i];
        }

        // ---- interleaved epilogue-A + stage B (W1 from LDS only) ----
        f32x4 acc2[2][8];
#pragma unroll
        for (int xt = 0; xt < 2; ++xt)
#pragma unroll
            for (int nt = 0; nt < 8; ++nt) acc2[xt][nt] = (f32x4){0.f, 0.f, 0.f, 0.f};
#pragma unroll
        for (int ks = 0; ks < 4; ++ks) {
            f32x4 bm0 = *(const f32x4*)(miscs + (2 * ks) * 16 + kg * 4);
            f32x4 bm1 = *(const f32x4*)(miscs + (2 * ks + 1) * 16 + kg * 4);
            f16x8 pa[2];
#pragma unroll
            for (int xt = 0; xt < 2; ++xt) {
                f32x4 e0 = acc[xt][2 * ks] + bm0;
                f32x4 e1 = acc[xt][2 * ks + 1] + bm1;
#pragma unroll
                for (int r = 0; r < 4; ++r) {
                    e0[r] = e0[r] > 0.f ? e0[r] : 0.f;
                    e1[r] = e1[r] > 0.f ? e1[r] : 0.f;
                }
                u32x4 ph = {pk2(e0[0], e0[1]), pk2(e0[2], e0[3]),
                            pk2(e1[0], e1[1]), pk2(e1[2], e1[3])};
                pa[xt] = __builtin_bit_cast(f16x8, ph);
            }
#pragma unroll
            for (int nt = 0; nt < 8; ++nt) {
                f16x8 wb = *(const f16x8*)(w1s + ((nt * 4 + ks) * 64 + lane) * 8);
#pragma unroll
                for (int xt = 0; xt < 2; ++xt)
                    acc2[xt][nt] = mfma16(pa[xt], wb, acc2[xt][nt]);
            }
        }

        // ---- epilogue B: accumulate relu(h2+b1).wmean into macc ----
#pragma unroll
        for (int nt = 0; nt < 8; ++nt) {
            float bb = b1s[nt * 16 + lm];
            float wm = miscs[HID + nt * 16 + lm];
#pragma unroll
            for (int xt = 0; xt < 2; ++xt)
#pragma unroll
                for (int r = 0; r < 4; ++r) {
                    float v = acc2[xt][nt][r] + bb;
                    v = v > 0.f ? v : 0.f;
                    macc[xt][r] += v * wm;
                }
        }
        __syncthreads();   // wefs writes visible before next u's reads
    }

    // one 16-lane reduce for the whole coset sum
#pragma unroll
    for (int off = 1; off < 16; off <<= 1)
#pragma unroll
        for (int xt = 0; xt < 2; ++xt)
#pragma unroll
            for (int r = 0; r < 4; ++r)
                macc[xt][r] += __shfl_xor(macc[xt][r], off, 64);
    if (lm == 0) {
#pragma unroll
        for (int xt = 0; xt < 2; ++xt)
#pragma unroll
            for (int r = 0; r < 4; ++r)
                out[(unsigned)(xbase + xt * 16 + kg * 4 + r) * NACT + a] =
                    macc[xt][r] * (1.f / 6.f) + cb;
    }
}

extern "C" void kernel_launch(void* const* d_in, const int* in_sizes, int n_in,
                              void* d_out, int out_size, void* d_ws, size_t ws_size,
                              hipStream_t stream) {
    const float* x       = (const float*)d_in[0];
    const float* eqw     = (const float*)d_in[1];
    const float* eq_bias = (const float*)d_in[2];
    const float* W1      = (const float*)d_in[3];
    const float* b1      = (const float*)d_in[4];
    const float* Wout    = (const float*)d_in[5];
    const float* bout    = (const float*)d_in[6];
    float* out           = (float*)d_out;

    char* ws = (char*)d_ws;
    unsigned short* weff = (unsigned short*)(ws + WEFF_OFF);
    unsigned short* xhb  = (unsigned short*)(ws + XH_OFF);
    unsigned short* w1f  = (unsigned short*)(ws + W1F_OFF);
    float* misc   = (float*)(ws + MISC_OFF);
    float* Acan   = (float*)(ws + ABUF_OFF);

    hipLaunchKernelGGL(prep_stage1, dim3(561), dim3(256), 0, stream,
                       x, W1, eq_bias, Wout, bout, eqw, misc, xhb, w1f, Acan);
    hipLaunchKernelGGL(weff_stage2, dim3(120), dim3(256), 0, stream,
                       Acan, weff);
    hipLaunchKernelGGL(mlp_mfma, dim3(640), dim3(128), 0, stream,
                       xhb, weff, w1f, b1, misc, out);
}

// Round 20
// 40.195 us; speedup vs baseline: 1.4142x; 1.0273x over previous
//
#include <hip/hip_runtime.h>

typedef _Float16 f16;
typedef __attribute__((ext_vector_type(8))) _Float16 f16x8;
typedef __attribute__((ext_vector_type(4))) float f32x4;
typedef __attribute__((ext_vector_type(4))) unsigned int u32x4;
typedef __attribute__((ext_vector_type(8))) unsigned short ushort8;

#define QF   64
#define GG   120
#define HID  128
#define NACT 20
#define BTOT 2048

// ---- workspace layout (bytes) ----
#define WEFF_OFF 0u           // 120 * 16KB f16 frag-order = 1,966,080
#define XH_OFF   1966080u     // 2048*64 f16 = 262,144
#define W1F_OFF  2490368u     // 32KB f16 frag-order (k-permuted)
#define MISC_OFF 2523136u     // bmean[128], wmean[128], cb (1088 B)
#define ABUF_OFF 2524224u     // A_canon: 5*64*128 f32 = 163,840

template <typename T>
__device__ __forceinline__ void keepv(T& v) { asm volatile("" : "+v"(v)); }

// ---- packed-nibble permutation helpers (register-only) ----
__device__ __forceinline__ unsigned idx_to_packed(int i) {
    unsigned avail = 0x43210u, pp = 0u;
    const int fct[4] = {24, 6, 2, 1};
#pragma unroll
    for (int k = 0; k < 4; ++k) {
        int d = i / fct[k]; i -= d * fct[k];
        pp |= ((avail >> (4 * d)) & 0xFu) << (4 * k);
        unsigned mask = (1u << (4 * d)) - 1u;
        avail = (avail & mask) | ((avail >> 4) & ~mask);
    }
    pp |= (avail & 0xFu) << 16;
    return pp;
}

__device__ __forceinline__ int packed_to_idx(unsigned pp) {
    const int fct[4] = {24, 6, 2, 1};
    int idx = 0;
#pragma unroll
    for (int k = 0; k < 4; ++k) {
        unsigned pk = (pp >> (4 * k)) & 0xFu;
        int c = 0;
#pragma unroll
        for (int j = k + 1; j < 5; ++j)
            c += (int)(((pp >> (4 * j)) & 0xFu) < pk);
        idx += c * fct[k];
    }
    return idx;
}

__device__ __forceinline__ unsigned compose_packed(unsigned pa, unsigned pb) {
    unsigned pc = 0;
#pragma unroll
    for (int k = 0; k < 5; ++k) {
        unsigned bk = (pb >> (4 * k)) & 0xFu;
        pc |= ((pa >> (4 * bk)) & 0xFu) << (4 * k);
    }
    return pc;
}

__device__ __forceinline__ unsigned invert_packed(unsigned pp) {
    unsigned pi = 0;
#pragma unroll
    for (int k = 0; k < 5; ++k)
        pi |= (unsigned)k << (4 * ((pp >> (4 * k)) & 0xFu));
    return pi;
}

// i-th element of S4 (perms of {0,1,2,3}, slot4 = 4), packed
__device__ __forceinline__ unsigned s4_packed(int i) {
    unsigned avail = 0x3210u, pp = 0u;
    const int f3[3] = {6, 2, 1};
#pragma unroll
    for (int k = 0; k < 3; ++k) {
        int d = i / f3[k]; i -= d * f3[k];
        pp |= ((avail >> (4 * d)) & 0xFu) << (4 * k);
        unsigned mask = (1u << (4 * d)) - 1u;
        avail = (avail & mask) | ((avail >> 4) & ~mask);
    }
    pp |= (avail & 0xFu) << 12;
    pp |= 4u << 16;
    return pp;
}

// transposition (t 4); t=4 -> identity (self-inverse)
__device__ __forceinline__ unsigned crep_pp(int t) {
    unsigned pp = 0x43210u;
    pp &= ~(0xFu << (4 * t));
    pp &= ~(0xFu << 16);
    pp |= 4u << (4 * t);
    pp |= (unsigned)t << 16;
    return pp;
}

// fpt[v][r] with ppi = v^-1 packed: output bit (4-k) = r bit (4-ppi[k]); top bit kept
__device__ __forceinline__ int bitperm_r(unsigned ppi, int r) {
    int val = r & 32;
#pragma unroll
    for (int k = 0; k < 5; ++k) {
        int pik = (ppi >> (4 * k)) & 0xF;
        val |= ((r >> (4 - pik)) & 1) << (4 - k);
    }
    return val;
}

// e-th member (e in 0..5) of coset a (perms with p0=i, p1=j), as perm index
__device__ __forceinline__ int coset_member(int a, int e) {
    int i = a >> 2, jj = a & 3;
    int j = jj + (jj >= i ? 1 : 0);
    unsigned mask = 0x1Fu & ~(1u << i) & ~(1u << j);
    int d0 = __builtin_ctz(mask); mask &= mask - 1u;
    int d1 = __builtin_ctz(mask); mask &= mask - 1u;
    int d2 = __builtin_ctz(mask);
    int k0 = e >> 1;
    int p2 = k0 == 0 ? d0 : (k0 == 1 ? d1 : d2);
    int r0 = k0 == 0 ? d1 : d0;
    int r1 = k0 == 2 ? d1 : d2;
    int p3 = (e & 1) ? r1 : r0;
    int p4 = (e & 1) ? r0 : r1;
    unsigned pp = (unsigned)i | ((unsigned)j << 4) | ((unsigned)p2 << 8)
                | ((unsigned)p3 << 12) | ((unsigned)p4 << 16);
    return packed_to_idx(pp);
}

__device__ __forceinline__ unsigned short f2h(float f) {
    f16 h = (f16)f;
    return __builtin_bit_cast(unsigned short, h);
}
// pack two floats to f16 pair (RTN) in a u32
__device__ __forceinline__ unsigned pk2(float a, float b) {
    return (unsigned)f2h(a) | ((unsigned)f2h(b) << 16);
}

// K1: fused prep. A_canon[c] = A[crep_c] (5 canonical matrices).
__global__ void prep_stage1(const float* __restrict__ x, const float* __restrict__ W1,
                            const float* __restrict__ eq_bias, const float* __restrict__ Wout,
                            const float* __restrict__ bout, const float* __restrict__ eqw,
                            float* __restrict__ misc,
                            unsigned short* __restrict__ xh,
                            unsigned short* __restrict__ w1f, float* __restrict__ Acan) {
    __shared__ int sg[24];
    __shared__ int sq[24][8];
    int b = blockIdx.x, t = threadIdx.x;
    if (b < 40) {
        int c = b >> 3, rbase = (b & 7) * 8;
        if (t < 24) sg[t] = packed_to_idx(compose_packed(s4_packed(t), crep_pp(c)));
        if (t < 192) {
            int si = t >> 3;
            sq[si][t & 7] = bitperm_r(invert_packed(s4_packed(si)), rbase + (t & 7));
        }
        __syncthreads();
        int h4 = (t & 31) * 4, rslot = t >> 5;
        f32x4 acc = {0.f, 0.f, 0.f, 0.f};
#pragma unroll
        for (int si = 0; si < 24; ++si) {
            f32x4 v = *(const f32x4*)(eqw + (unsigned)(sg[si] * QF + sq[si][rslot]) * HID + h4);
            acc = acc + v;
        }
        *(f32x4*)(Acan + (unsigned)(c * QF + rbase + rslot) * HID + h4) = acc;
    } else if (b < 552) {                 // x -> f16 (single, RTN)
        int idx = (b - 40) * 256 + t;     // < 131072
        xh[idx] = f2h(x[idx]);
    } else if (b < 560) {                 // W1 -> f16 B-frags, k-permuted
        int idx = (b - 552) * 256 + t;    // < 2048
        int fg = idx >> 6, lane = idx & 63;
        int nt = fg >> 2, ks = fg & 3;
        int n = nt * 16 + (lane & 15), kg = lane >> 4;
        ushort8 v;
#pragma unroll
        for (int j = 0; j < 8; ++j) {
            int h = ks * 32 + ((j >> 2) << 4) + (kg << 2) + (j & 3);
            v[j] = f2h(W1[h * HID + n]);
        }
        *(ushort8*)(w1f + idx * 8) = v;
    } else {                              // misc
        if (t < HID) {
            float s = 0.f;
            for (int g = 0; g < GG; ++g) s += eq_bias[g * HID + t];
            misc[t] = s * (1.f / GG);
            float wv = 0.f;
            for (int n = 0; n < NACT; ++n) wv += Wout[t * NACT + n];
            misc[HID + t] = wv * (1.f / NACT);
            if (t == 0) {
                float c = 0.f;
                for (int n = 0; n < NACT; ++n) c += bout[n];
                misc[2 * HID] = c * (1.f / NACT);
            }
        }
    }
}

// K2: Weff[u][q][h] = (1/G) sum_{c=0..4} A_canon[c][fpt[crep_c∘u^-1][q]][h]
// Emit f16 A-frags: [hm(8)][ks(2)][lane(64)] x ushort8
__global__ void weff_stage2(const float* __restrict__ Acan,
                            unsigned short* __restrict__ weff) {
    __shared__ float Wacc[HID][QF + 1];
    __shared__ int rp[5][64];
    int u = blockIdx.x, t = threadIdx.x;
    unsigned upk = idx_to_packed(u);
    for (int i = t; i < 5 * 64; i += 256)
        rp[i >> 6][i & 63] = bitperm_r(compose_packed(upk, crep_pp(i >> 6)), i & 63);
    __syncthreads();
    int h = t & 127, qg = t >> 7;
    for (int i = 0; i < 32; ++i) {
        int q = qg * 32 + i;
        float s = 0.f;
#pragma unroll
        for (int c = 0; c < 5; ++c)
            s += Acan[(unsigned)(c * QF + rp[c][q]) * HID + h];
        Wacc[h][q] = s * (1.f / GG);
    }
    __syncthreads();
    for (int e = t; e < 1024; e += 256) {
        int fg = e >> 6, lane = e & 63;
        int hm = fg >> 1, ks = fg & 1;
        int hh = hm * 16 + (lane & 15), q0 = ks * 32 + (lane >> 4) * 8;
        ushort8 v;
#pragma unroll
        for (int j = 0; j < 8; ++j) v[j] = f2h(Wacc[hh][q0 + j]);
        *(ushort8*)(weff + (unsigned)(u * 16 + fg) * 64 * 8 + lane * 8) = v;
    }
}

__device__ __forceinline__ f32x4 mfma16(f16x8 a, f16x8 b, f32x4 c) {
    return __builtin_amdgcn_mfma_f32_16x16x32_f16(a, b, c, 0, 0, 0);
}

// K3: fused MLP + coset reduce. 1280 blocks (64 row-tiles x 20 cosets) x 128 thr,
// 16 rows/wave. weff in LDS (16KB, reg-prefetch dbuf pattern); W1 streamed from
// global (32KB, L1-resident, short-lived temps). LDS ~18KB -> 5 blocks/CU
// resident = 2.5 waves/SIMD (2x R19).
__global__ __launch_bounds__(128, 2)
void mlp_mfma(const unsigned short* __restrict__ xh,
              const unsigned short* __restrict__ weff,
              const unsigned short* __restrict__ w1f,
              const float* __restrict__ b1,
              const float* __restrict__ misc,
              float* __restrict__ out) {
    __shared__ __align__(16) unsigned short wefs[8192];      // 16KB
    __shared__ float miscs[2 * HID];
    __shared__ float b1s[HID];

    int bid0 = blockIdx.x;
    int bid = (bid0 & 7) * 160 + (bid0 >> 3);  // XCD-chunked, bijective (1280=8*160)
    int tile = bid & 63, a = bid >> 6;
    int rowbase = tile * 32;
    int t = threadIdx.x;                  // 0..127
    int w = t >> 6, lane = t & 63;
    int lm = lane & 15, kg = lane >> 4;
    int xbase = rowbase + w * 16;

    int u0 = coset_member(a, 0);
#pragma unroll
    for (int i = 0; i < 8; ++i)
        *(u32x4*)(wefs + (i * 128 + t) * 8) =
            *(const u32x4*)(weff + (unsigned)u0 * 8192 + (i * 128 + t) * 8);
    miscs[t] = misc[t];
    miscs[128 + t] = misc[128 + t];
    b1s[t] = b1[t];
    float cb = misc[2 * HID];

    // pin X frags (B-operand of swapped stage A): [ks], single f16, 16 rows/wave
    f16x8 xb[2];
#pragma unroll
    for (int ks = 0; ks < 2; ++ks) {
        int off = (xbase + lm) * QF + ks * 32 + kg * 8;
        xb[ks] = *(const f16x8*)(xh + off);
        keepv(xb[ks]);
    }
    __syncthreads();

    float macc[4] = {0.f, 0.f, 0.f, 0.f};

#pragma unroll 1
    for (int ui = 0; ui < 6; ++ui) {
        bool hasNext = (ui < 5);
        u32x4 pf[8];
        if (hasNext) {
            int un = coset_member(a, ui + 1);
            const unsigned short* wsrc = weff + (unsigned)un * 8192;
#pragma unroll
            for (int i = 0; i < 8; ++i)
                pf[i] = *(const u32x4*)(wsrc + (i * 128 + t) * 8);
        }

        // ---- stage A (swapped): lane holds E for x-row xbase+lm, h = hm*16+kg*4+r
        f32x4 acc[8];
#pragma unroll
        for (int hm = 0; hm < 8; ++hm) acc[hm] = (f32x4){0.f, 0.f, 0.f, 0.f};
#pragma unroll
        for (int hm = 0; hm < 8; ++hm)
#pragma unroll
            for (int ks = 0; ks < 2; ++ks) {
                f16x8 wf = *(const f16x8*)(wefs + ((hm * 2 + ks) * 64 + lane) * 8);
                acc[hm] = mfma16(wf, xb[ks], acc[hm]);
            }

        __syncthreads();   // all waves done reading wefs
        if (hasNext) {
#pragma unroll
            for (int i = 0; i < 8; ++i)
                *(u32x4*)(wefs + (i * 128 + t) * 8) = pf[i];
        }

        // ---- interleaved epilogue-A + stage B (W1 streamed from global/L1) ----
        f32x4 acc2[8];
#pragma unroll
        for (int nt = 0; nt < 8; ++nt) acc2[nt] = (f32x4){0.f, 0.f, 0.f, 0.f};
#pragma unroll
        for (int ks = 0; ks < 4; ++ks) {
            f32x4 bm0 = *(const f32x4*)(miscs + (2 * ks) * 16 + kg * 4);
            f32x4 bm1 = *(const f32x4*)(miscs + (2 * ks + 1) * 16 + kg * 4);
            f32x4 e0 = acc[2 * ks] + bm0;
            f32x4 e1 = acc[2 * ks + 1] + bm1;
#pragma unroll
            for (int r = 0; r < 4; ++r) {
                e0[r] = e0[r] > 0.f ? e0[r] : 0.f;
                e1[r] = e1[r] > 0.f ? e1[r] : 0.f;
            }
            u32x4 ph = {pk2(e0[0], e0[1]), pk2(e0[2], e0[3]),
                        pk2(e1[0], e1[1]), pk2(e1[2], e1[3])};
            f16x8 pa = __builtin_bit_cast(f16x8, ph);
#pragma unroll
            for (int nt = 0; nt < 8; ++nt) {
                f16x8 wb = *(const f16x8*)(w1f + ((nt * 4 + ks) * 64 + lane) * 8);
                acc2[nt] = mfma16(pa, wb, acc2[nt]);
            }
        }

        // ---- epilogue B: accumulate relu(h2+b1).wmean into macc ----
#pragma unroll
        for (int nt = 0; nt < 8; ++nt) {
            float bb = b1s[nt * 16 + lm];
            float wm = miscs[HID + nt * 16 + lm];
#pragma unroll
            for (int r = 0; r < 4; ++r) {
                float v = acc2[nt][r] + bb;
                v = v > 0.f ? v : 0.f;
                macc[r] += v * wm;
            }
        }
        __syncthreads();   // wefs writes visible before next u's reads
    }

    // one 16-lane reduce for the whole coset sum
#pragma unroll
    for (int off = 1; off < 16; off <<= 1)
#pragma unroll
        for (int r = 0; r < 4; ++r)
            macc[r] += __shfl_xor(macc[r], off, 64);
    if (lm == 0) {
#pragma unroll
        for (int r = 0; r < 4; ++r)
            out[(unsigned)(xbase + kg * 4 + r) * NACT + a] =
                macc[r] * (1.f / 6.f) + cb;
    }
}

extern "C" void kernel_launch(void* const* d_in, const int* in_sizes, int n_in,
                              void* d_out, int out_size, void* d_ws, size_t ws_size,
                              hipStream_t stream) {
    const float* x       = (const float*)d_in[0];
    const float* eqw     = (const float*)d_in[1];
    const float* eq_bias = (const float*)d_in[2];
    const float* W1      = (const float*)d_in[3];
    const float* b1      = (const float*)d_in[4];
    const float* Wout    = (const float*)d_in[5];
    const float* bout    = (const float*)d_in[6];
    float* out           = (float*)d_out;

    char* ws = (char*)d_ws;
    unsigned short* weff = (unsigned short*)(ws + WEFF_OFF);
    unsigned short* xhb  = (unsigned short*)(ws + XH_OFF);
    unsigned short* w1f  = (unsigned short*)(ws + W1F_OFF);
    float* misc   = (float*)(ws + MISC_OFF);
    float* Acan   = (float*)(ws + ABUF_OFF);

    hipLaunchKernelGGL(prep_stage1, dim3(561), dim3(256), 0, stream,
                       x, W1, eq_bias, Wout, bout, eqw, misc, xhb, w1f, Acan);
    hipLaunchKernelGGL(weff_stage2, dim3(120), dim3(256), 0, stream,
                       Acan, weff);
    hipLaunchKernelGGL(mlp_mfma, dim3(1280), dim3(128), 0, stream,
                       xhb, weff, w1f, b1, misc, out);
}